// Round 14
// baseline (117.675 us; speedup 1.0000x reference)
//
#include <hip/hip_runtime.h>

// Binary-weight 3x3 conv via implicit GEMM on int8 MFMA.
// out[co, p] = (1/26) * sum_k wb[co,k] * q26(im2col(x))[k,p],  exact i32 accum.
// Round 14: faithful m201-style phase port of R7. Per step (BK=64 ci):
//   WAITV(8/6) gate + barrier  [stage(u) globally resident]
//   4 phases (n-pairs): {ds_read subtile; 1 stage-chunk(u+3); barrier;
//                        lgkmcnt(0)+sched_barrier; setprio(1); 8/8/8/4 MFMA;
//                        setprio(0); barrier}
// Reads feed the SAME phase (per-wave lgkm0 -> waves slip, LDS drain overlaps
// MFMA). Counted vmcnt never 0 mid-loop. Staging/swizzle/epilogue = R7 bytes.

#define N_ 32
#define C_ 256
#define H_ 56
#define W_ 56
#define HP 58
#define SPATIAL (H_ * W_)          // 3136
#define P_TOTAL (N_ * SPATIAL)     // 100352
#define BNP 224
#define NBLK (P_TOTAL / BNP)       // 448
#define NSUB 36                    // 4 ci-slices(64) * 9 taps
#define QSCALE 26.0f
#define QINV (1.0f / 26.0f)

typedef __attribute__((ext_vector_type(4))) int int32x4;

#define GLOAD_LDS16(g, l) __builtin_amdgcn_global_load_lds(                 \
    (const __attribute__((address_space(1))) void*)(g),                     \
    (__attribute__((address_space(3))) void*)(l), 16, 0, 0)

#define WAITV(N) asm volatile("s_waitcnt vmcnt(" #N ")" ::: "memory")
#define LGKM0()  do { asm volatile("s_waitcnt lgkmcnt(0)" ::: "memory");    \
                      __builtin_amdgcn_sched_barrier(0); } while (0)
#define BAR()    __builtin_amdgcn_s_barrier()

// ---------------- prep kernels (verified R7) ----------------

__global__ void xform_w(const float* __restrict__ w, char* __restrict__ wt) {
    const int co = blockIdx.x;
    const int ci = threadIdx.x;
    const float* wp = w + ((size_t)co * C_ + ci) * 9;
    #pragma unroll
    for (int tap = 0; tap < 9; ++tap)
        wt[((size_t)tap * C_ + co) * C_ + ci] = (wp[tap] >= 0.f) ? (char)1 : (char)-1;
}

// NCHW f32 -> padded NHWC i8 (q = clamp(rint(26x)); pad = -26). Block = (n,h).
__global__ __launch_bounds__(256) void xform_x(const float* __restrict__ x,
                                               unsigned char* __restrict__ xt) {
    __shared__ unsigned char lds8[64 * 272];
    const int b = blockIdx.x;                  // n*56 + h
    const int n = b / H_;
    const int h = b - n * H_;
    const int t = threadIdx.x;
    const int wq = t >> 6;
    const int wv = t & 63;
    const float* xp = x + (((size_t)n * C_ + wq * 64) * H_ + h) * W_ + wv;

    #pragma unroll 4
    for (int c4 = 0; c4 < 64; c4 += 4) {
        unsigned int pk = 0;
        #pragma unroll
        for (int j = 0; j < 4; ++j) {
            float v = (wv < W_) ? xp[(size_t)(c4 + j) * SPATIAL] : 0.f;
            int q = (int)rintf(v * QSCALE);
            q = q < -127 ? -127 : (q > 127 ? 127 : q);
            pk |= ((unsigned int)(q & 255)) << (8 * j);
        }
        if (wv < W_)
            *reinterpret_cast<unsigned int*>(&lds8[wv * 272 + wq * 64 + c4]) = pk;
    }
    __syncthreads();

    unsigned char* rowp = xt + (((size_t)n * HP + h + 1) * HP) * C_;
    {
        const int ww = t & 63, cq = t >> 6;
        if (ww < W_) {
            #pragma unroll
            for (int j = 0; j < 4; ++j) {
                int32x4 v = *reinterpret_cast<const int32x4*>(
                    &lds8[ww * 272 + cq * 64 + j * 16]);
                *reinterpret_cast<int32x4*>(rowp + (size_t)(ww + 1) * C_ + cq * 64 + j * 16) = v;
            }
        }
    }
    if (t < 64) {
        reinterpret_cast<unsigned int*>(rowp)[t] = 0xE6E6E6E6u;
        reinterpret_cast<unsigned int*>(rowp + (size_t)57 * C_)[t] = 0xE6E6E6E6u;
    }
    if (h == 0) {
        unsigned int* r0  = reinterpret_cast<unsigned int*>(xt + ((size_t)n * HP) * HP * C_);
        unsigned int* r57 = reinterpret_cast<unsigned int*>(xt + (((size_t)n * HP + 57) * HP) * C_);
        for (int idx = t; idx < HP * C_ / 4; idx += 256) {
            r0[idx]  = 0xE6E6E6E6u;
            r57[idx] = 0xE6E6E6E6u;
        }
    }
}

// ---------------- main GEMM ----------------
// grid = 448 blocks (XCD-swizzled), 512 threads = 8 waves (4 co x 2 p).
// Wave (wm,wn): 64 co x 112 p = 4x7 16x16x64 i8 fragments.
// Step u: cbh = u/9 (64-ci slice), tap = u%9; quad LDS buffers q = u&3.

__global__ __launch_bounds__(512, 2) void bgemm(const unsigned char* __restrict__ xt,
                                                const unsigned char* __restrict__ wt,
                                                float* __restrict__ out) {
    extern __shared__ char smem[];
    const int t = threadIdx.x;
    const int lane = t & 63;
    const int wid = t >> 6;
    const int wm = wid >> 1;          // 0..3 (co)
    const int wn = wid & 1;           // 0..1 (p)
    const bool lw = (t < 384);        // waves 0..5: 4 loads/stage, else 3
    const int bid = blockIdx.x;
    const int blk = (bid & 7) * (NBLK / 8) + (bid >> 3);   // XCD-chunked (bijective)
    const int n = blk / 14;
    const int pq = blk % 14;
    const int sp0 = pq * BNP;
    const int h0 = pq * 4;

    // staging: chunk c -> row=c>>2, slot=c&3, src chunk kc=(slot-(row>>1))&3.
    int a_off[2], x_off[2];
    #pragma unroll
    for (int i = 0; i < 2; ++i) {
        const int c = t + 512 * i;
        const int row = c >> 2;
        const int kc = ((c & 3) - (row >> 1)) & 3;
        a_off[i] = row * C_ + kc * 16;
    }
    {
        int c = t;
        int row = c >> 2;
        int kc = ((c & 3) - (row >> 1)) & 3;
        x_off[0] = ((n * HP + h0 + row / W_) * HP + (row % W_)) * C_ + kc * 16;
        c = t + 512;
        row = c >> 2;
        const int rowc = (row < BNP) ? row : 0;
        kc = ((c & 3) - (row >> 1)) & 3;
        x_off[1] = ((n * HP + h0 + rowc / W_) * HP + (rowc % W_)) * C_ + kc * 16;
    }

    // fragment-read byte offsets (64B rows, slot=(g+(r>>1))&3)
    const int g = lane >> 4;
    int aoff[4], boff[7];
    #pragma unroll
    for (int m = 0; m < 4; ++m) {
        const int r = wm * 64 + m * 16 + (lane & 15);
        aoff[m] = r * 64 + (((g + (r >> 1)) & 3) << 4);
    }
    #pragma unroll
    for (int nn = 0; nn < 7; ++nn) {
        const int r = wn * 112 + nn * 16 + (lane & 15);
        boff[nn] = r * 64 + (((g + (r >> 1)) & 3) << 4);
    }

    int32x4 acc[4][7];
    #pragma unroll
    for (int m = 0; m < 4; ++m)
        #pragma unroll
        for (int nn = 0; nn < 7; ++nn)
            acc[m][nn] = (int32x4){0, 0, 0, 0};

    auto sstage_all = [&](int u) {   // prologue only: all 4 chunks at once
        const int cbh = u / 9;
        const int tap = u - cbh * 9;
        const int kh = tap / 3, kw = tap - kh * 3;
        const int koff = cbh * 64;
        const int q = u & 3;
        char* Aq = smem + q * 16384;
        char* Bq = smem + 65536 + q * 14336;
        const unsigned char* asrc = wt + (size_t)tap * (C_ * C_) + koff;
        const unsigned char* bsrc = xt + (kh * HP + kw) * C_ + koff;
        GLOAD_LDS16(asrc + a_off[0], Aq + t * 16);
        GLOAD_LDS16(asrc + a_off[1], Aq + (t + 512) * 16);
        GLOAD_LDS16(bsrc + x_off[0], Bq + t * 16);
        if (lw)
            GLOAD_LDS16(bsrc + x_off[1], Bq + (t + 512) * 16);
    };

    // prologue: 3 stages in flight
    sstage_all(0); sstage_all(1); sstage_all(2);

    for (int u = 0; u < NSUB; ++u) {
        // gate: stage(u) resident; stages u+1,u+2 may stay in flight
        if (u < NSUB - 2)      { if (lw) WAITV(8); else WAITV(6); }
        else if (u == NSUB - 2){ if (lw) WAITV(4); else WAITV(3); }
        else                   { WAITV(0); }
        BAR();

        const int q = u & 3;
        const char* Aq = smem + q * 16384;
        const char* Bq = smem + 65536 + q * 14336;

        // stage(u+3) source/dest (guarded by st at each gload)
        const bool st = (u + 3 < NSUB);
        const int u3 = st ? (u + 3) : 0;
        const int cbh3 = u3 / 9;
        const int tap3 = u3 - cbh3 * 9;
        char* Aq3 = smem + (u3 & 3) * 16384;
        char* Bq3 = smem + 65536 + (u3 & 3) * 14336;
        const unsigned char* asrc3 = wt + (size_t)tap3 * (C_ * C_) + cbh3 * 64;
        const unsigned char* bsrc3 = xt + ((tap3 / 3) * HP + (tap3 - (tap3 / 3) * 3)) * C_ + cbh3 * 64;

        int32x4 af[4], bf0, bf1;

        // ---- phase 0: reads a0-3, b0, b1; stage chunk0; MFMA n0,n1 ----
        af[0] = *reinterpret_cast<const int32x4*>(Aq + aoff[0]);
        af[1] = *reinterpret_cast<const int32x4*>(Aq + aoff[1]);
        af[2] = *reinterpret_cast<const int32x4*>(Aq + aoff[2]);
        af[3] = *reinterpret_cast<const int32x4*>(Aq + aoff[3]);
        bf0 = *reinterpret_cast<const int32x4*>(Bq + boff[0]);
        bf1 = *reinterpret_cast<const int32x4*>(Bq + boff[1]);
        if (st) GLOAD_LDS16(asrc3 + a_off[0], Aq3 + t * 16);
        BAR(); LGKM0();
        __builtin_amdgcn_s_setprio(1);
        #pragma unroll
        for (int m = 0; m < 4; ++m) {
            acc[m][0] = __builtin_amdgcn_mfma_i32_16x16x64_i8(af[m], bf0, acc[m][0], 0, 0, 0);
            acc[m][1] = __builtin_amdgcn_mfma_i32_16x16x64_i8(af[m], bf1, acc[m][1], 0, 0, 0);
        }
        __builtin_amdgcn_s_setprio(0);
        BAR();

        // ---- phase 1: reads b2, b3; stage chunk1; MFMA n2,n3 ----
        bf0 = *reinterpret_cast<const int32x4*>(Bq + boff[2]);
        bf1 = *reinterpret_cast<const int32x4*>(Bq + boff[3]);
        if (st) GLOAD_LDS16(asrc3 + a_off[1], Aq3 + (t + 512) * 16);
        BAR(); LGKM0();
        __builtin_amdgcn_s_setprio(1);
        #pragma unroll
        for (int m = 0; m < 4; ++m) {
            acc[m][2] = __builtin_amdgcn_mfma_i32_16x16x64_i8(af[m], bf0, acc[m][2], 0, 0, 0);
            acc[m][3] = __builtin_amdgcn_mfma_i32_16x16x64_i8(af[m], bf1, acc[m][3], 0, 0, 0);
        }
        __builtin_amdgcn_s_setprio(0);
        BAR();

        // ---- phase 2: reads b4, b5; stage chunk2; MFMA n4,n5 ----
        bf0 = *reinterpret_cast<const int32x4*>(Bq + boff[4]);
        bf1 = *reinterpret_cast<const int32x4*>(Bq + boff[5]);
        if (st) GLOAD_LDS16(bsrc3 + x_off[0], Bq3 + t * 16);
        BAR(); LGKM0();
        __builtin_amdgcn_s_setprio(1);
        #pragma unroll
        for (int m = 0; m < 4; ++m) {
            acc[m][4] = __builtin_amdgcn_mfma_i32_16x16x64_i8(af[m], bf0, acc[m][4], 0, 0, 0);
            acc[m][5] = __builtin_amdgcn_mfma_i32_16x16x64_i8(af[m], bf1, acc[m][5], 0, 0, 0);
        }
        __builtin_amdgcn_s_setprio(0);
        BAR();

        // ---- phase 3: read b6; stage chunk3 (lw); MFMA n6 ----
        bf0 = *reinterpret_cast<const int32x4*>(Bq + boff[6]);
        if (st && lw) GLOAD_LDS16(bsrc3 + x_off[1], Bq3 + (t + 512) * 16);
        BAR(); LGKM0();
        __builtin_amdgcn_s_setprio(1);
        #pragma unroll
        for (int m = 0; m < 4; ++m)
            acc[m][6] = __builtin_amdgcn_mfma_i32_16x16x64_i8(af[m], bf0, acc[m][6], 0, 0, 0);
        __builtin_amdgcn_s_setprio(0);
        BAR();
    }

    // epilogue: D col = lane&15 (p), row = (lane>>4)*4 + j (co); scale by 1/26
    #pragma unroll
    for (int m = 0; m < 4; ++m) {
        #pragma unroll
        for (int j = 0; j < 4; ++j) {
            const int co = wm * 64 + m * 16 + (lane >> 4) * 4 + j;
            float* op = out + (size_t)(n * C_ + co) * SPATIAL + sp0 + wn * 112 + (lane & 15);
            #pragma unroll
            for (int nn = 0; nn < 7; ++nn)
                op[nn * 16] = (float)acc[m][nn][j] * QINV;
        }
    }
}

// ---------------- fallback (round-1 f32 direct conv) ----------------

__global__ __launch_bounds__(128) void bconv_f32_kernel(
    const float* __restrict__ x,
    const float* __restrict__ w,
    float* __restrict__ out)
{
    const int tx = threadIdx.x;
    const int ty = threadIdx.y;
    const int nc = blockIdx.x;
    const int co = nc & 255;
    const int h  = blockIdx.y * 8 + ty;
    const int w0 = tx * 4;
    if (tx >= 14) return;

    const float* xn = x + (size_t)(nc >> 8) * (C_ * H_ * W_);
    const float* wc = w + (size_t)co * (C_ * 9);
    float acc0 = 0.f, acc1 = 0.f, acc2 = 0.f, acc3 = 0.f;
    const bool rv0 = (h > 0), rv2 = (h < H_ - 1);
    const bool cvL = (tx != 0), cvR = (tx != 13);

    for (int ci = 0; ci < C_; ++ci) {
        const float* xc = xn + ci * (H_ * W_);
        const float* wk = wc + ci * 9;
        float v[3][6];
        #pragma unroll
        for (int r = 0; r < 3; ++r) {
            const bool rv = (r == 0) ? rv0 : (r == 2) ? rv2 : true;
            if (rv) {
                const float* rp = xc + (h + r - 1) * W_;
                const float4 m = *reinterpret_cast<const float4*>(rp + w0);
                v[r][1] = m.x; v[r][2] = m.y; v[r][3] = m.z; v[r][4] = m.w;
                v[r][0] = cvL ? rp[w0 - 1] : -1.0f;
                v[r][5] = cvR ? rp[w0 + 4] : -1.0f;
            } else {
                #pragma unroll
                for (int j = 0; j < 6; ++j) v[r][j] = -1.0f;
            }
        }
        #pragma unroll
        for (int r = 0; r < 3; ++r)
            #pragma unroll
            for (int c = 0; c < 3; ++c) {
                const float s = (wk[r * 3 + c] >= 0.f) ? 1.0f : -1.0f;
                acc0 = fmaf(s, v[r][c + 0], acc0);
                acc1 = fmaf(s, v[r][c + 1], acc1);
                acc2 = fmaf(s, v[r][c + 2], acc2);
                acc3 = fmaf(s, v[r][c + 3], acc3);
            }
    }
    float* op = out + ((size_t)nc * H_ + h) * W_ + w0;
    *reinterpret_cast<float4*>(op) = make_float4(acc0, acc1, acc2, acc3);
}

// ---------------- launch ----------------

extern "C" void kernel_launch(void* const* d_in, const int* in_sizes, int n_in,
                              void* d_out, int out_size, void* d_ws, size_t ws_size,
                              hipStream_t stream) {
    const float* x = (const float*)d_in[0];
    const float* w = (const float*)d_in[1];
    float* out = (float*)d_out;

    const size_t XT_OFF = 2u * 1024u * 1024u;                 // wt region (590KB)
    const size_t XT_BYTES = (size_t)N_ * HP * HP * C_;        // 27,557,888 (i8)
    const size_t NEEDED = XT_OFF + XT_BYTES;
    const int LDS_BYTES = 122880;   // A 4x16KB + B 4x14KB

    if (ws_size >= NEEDED) {
        char* wt = (char*)d_ws;
        unsigned char* xt = (unsigned char*)((char*)d_ws + XT_OFF);
        hipFuncSetAttribute((const void*)&bgemm,
                            hipFuncAttributeMaxDynamicSharedMemorySize, LDS_BYTES);
        xform_w<<<256, 256, 0, stream>>>(w, wt);
        xform_x<<<N_ * H_, 256, 0, stream>>>(x, xt);
        bgemm<<<NBLK, 512, LDS_BYTES, stream>>>(xt, (const unsigned char*)wt, out);
    } else {
        dim3 block(16, 8);
        dim3 grid(N_ * 256, H_ / 8);
        bconv_f32_kernel<<<grid, block, 0, stream>>>(x, w, out);
    }
}

// Round 15
// 98.384 us; speedup vs baseline: 1.1961x; 1.1961x over previous
//
#include <hip/hip_runtime.h>

// Binary-weight 3x3 conv via implicit GEMM on int8 MFMA.
// out[co, p] = (1/26) * sum_k wb[co,k] * q26(im2col(x))[k,p],  exact i32 accum.
// Round 15: BK=128 (two verified 64-ci halves per step), 18 steps instead of
// 36 -> halves the per-step fixed sync cost that all prior schedules shared.
// Double-buffered LDS (A 2x32KB + B 2x28KB = 120KB), R4-ledger sync:
// per step {WAITV(0); s_barrier; [reads h0; stage-A(u+1); MFMA 28];
//                               [reads h1; stage-B(u+1); MFMA 28]}.
// Staging bytes, swizzle, frag offsets, epilogue identical to R7 per half.

#define N_ 32
#define C_ 256
#define H_ 56
#define W_ 56
#define HP 58
#define SPATIAL (H_ * W_)          // 3136
#define P_TOTAL (N_ * SPATIAL)     // 100352
#define BNP 224
#define NBLK (P_TOTAL / BNP)       // 448
#define NSTEP 18                   // 2 ci-groups(128) * 9 taps
#define QSCALE 26.0f
#define QINV (1.0f / 26.0f)

typedef __attribute__((ext_vector_type(4))) int int32x4;

#define GLOAD_LDS16(g, l) __builtin_amdgcn_global_load_lds(                 \
    (const __attribute__((address_space(1))) void*)(g),                     \
    (__attribute__((address_space(3))) void*)(l), 16, 0, 0)

#define WAITV0() asm volatile("s_waitcnt vmcnt(0)" ::: "memory")

// ---------------- prep kernels (verified R7) ----------------

__global__ void xform_w(const float* __restrict__ w, char* __restrict__ wt) {
    const int co = blockIdx.x;
    const int ci = threadIdx.x;
    const float* wp = w + ((size_t)co * C_ + ci) * 9;
    #pragma unroll
    for (int tap = 0; tap < 9; ++tap)
        wt[((size_t)tap * C_ + co) * C_ + ci] = (wp[tap] >= 0.f) ? (char)1 : (char)-1;
}

// NCHW f32 -> padded NHWC i8 (q = clamp(rint(26x)); pad = -26). Block = (n,h).
__global__ __launch_bounds__(256) void xform_x(const float* __restrict__ x,
                                               unsigned char* __restrict__ xt) {
    __shared__ unsigned char lds8[64 * 272];
    const int b = blockIdx.x;                  // n*56 + h
    const int n = b / H_;
    const int h = b - n * H_;
    const int t = threadIdx.x;
    const int wq = t >> 6;
    const int wv = t & 63;
    const float* xp = x + (((size_t)n * C_ + wq * 64) * H_ + h) * W_ + wv;

    #pragma unroll 4
    for (int c4 = 0; c4 < 64; c4 += 4) {
        unsigned int pk = 0;
        #pragma unroll
        for (int j = 0; j < 4; ++j) {
            float v = (wv < W_) ? xp[(size_t)(c4 + j) * SPATIAL] : 0.f;
            int q = (int)rintf(v * QSCALE);
            q = q < -127 ? -127 : (q > 127 ? 127 : q);
            pk |= ((unsigned int)(q & 255)) << (8 * j);
        }
        if (wv < W_)
            *reinterpret_cast<unsigned int*>(&lds8[wv * 272 + wq * 64 + c4]) = pk;
    }
    __syncthreads();

    unsigned char* rowp = xt + (((size_t)n * HP + h + 1) * HP) * C_;
    {
        const int ww = t & 63, cq = t >> 6;
        if (ww < W_) {
            #pragma unroll
            for (int j = 0; j < 4; ++j) {
                int32x4 v = *reinterpret_cast<const int32x4*>(
                    &lds8[ww * 272 + cq * 64 + j * 16]);
                *reinterpret_cast<int32x4*>(rowp + (size_t)(ww + 1) * C_ + cq * 64 + j * 16) = v;
            }
        }
    }
    if (t < 64) {
        reinterpret_cast<unsigned int*>(rowp)[t] = 0xE6E6E6E6u;
        reinterpret_cast<unsigned int*>(rowp + (size_t)57 * C_)[t] = 0xE6E6E6E6u;
    }
    if (h == 0) {
        unsigned int* r0  = reinterpret_cast<unsigned int*>(xt + ((size_t)n * HP) * HP * C_);
        unsigned int* r57 = reinterpret_cast<unsigned int*>(xt + (((size_t)n * HP + 57) * HP) * C_);
        for (int idx = t; idx < HP * C_ / 4; idx += 256) {
            r0[idx]  = 0xE6E6E6E6u;
            r57[idx] = 0xE6E6E6E6u;
        }
    }
}

// ---------------- main GEMM ----------------
// grid = 448 blocks (XCD-swizzled), 512 threads = 8 waves (4 co x 2 p).
// Wave (wm,wn): 64 co x 112 p = 4x7 16x16x64 i8 fragments.
// Step u (18): cbh2 = u/9 (128-ci group), tap = u%9 (fastest: L2 tap reuse).
// LDS buf q=u&1: A q*32768 + half*16384; B 65536 + q*28672 + half*14336.

__global__ __launch_bounds__(512, 2) void bgemm(const unsigned char* __restrict__ xt,
                                                const unsigned char* __restrict__ wt,
                                                float* __restrict__ out) {
    extern __shared__ char smem[];
    const int t = threadIdx.x;
    const int lane = t & 63;
    const int wid = t >> 6;
    const int wm = wid >> 1;          // 0..3 (co)
    const int wn = wid & 1;           // 0..1 (p)
    const bool lw = (t < 384);
    const int bid = blockIdx.x;
    const int blk = (bid & 7) * (NBLK / 8) + (bid >> 3);   // XCD-chunked (bijective)
    const int n = blk / 14;
    const int pq = blk % 14;
    const int sp0 = pq * BNP;
    const int h0 = pq * 4;

    // staging (verified): chunk c -> row=c>>2, slot=c&3, src kc=(slot-(row>>1))&3
    int a_off[2], x_off[2];
    #pragma unroll
    for (int i = 0; i < 2; ++i) {
        const int c = t + 512 * i;
        const int row = c >> 2;
        const int kc = ((c & 3) - (row >> 1)) & 3;
        a_off[i] = row * C_ + kc * 16;
    }
    {
        int c = t;
        int row = c >> 2;
        int kc = ((c & 3) - (row >> 1)) & 3;
        x_off[0] = ((n * HP + h0 + row / W_) * HP + (row % W_)) * C_ + kc * 16;
        c = t + 512;
        row = c >> 2;
        const int rowc = (row < BNP) ? row : 0;
        kc = ((c & 3) - (row >> 1)) & 3;
        x_off[1] = ((n * HP + h0 + rowc / W_) * HP + (rowc % W_)) * C_ + kc * 16;
    }

    // fragment-read byte offsets (verified; within a 64-ci half)
    const int g = lane >> 4;
    int aoff[4], boff[7];
    #pragma unroll
    for (int m = 0; m < 4; ++m) {
        const int r = wm * 64 + m * 16 + (lane & 15);
        aoff[m] = r * 64 + (((g + (r >> 1)) & 3) << 4);
    }
    #pragma unroll
    for (int nn = 0; nn < 7; ++nn) {
        const int r = wn * 112 + nn * 16 + (lane & 15);
        boff[nn] = r * 64 + (((g + (r >> 1)) & 3) << 4);
    }

    int32x4 acc[4][7];
    #pragma unroll
    for (int m = 0; m < 4; ++m)
        #pragma unroll
        for (int nn = 0; nn < 7; ++nn)
            acc[m][nn] = (int32x4){0, 0, 0, 0};

    // stage one 64-ci half of step u: part 0 = A-half, part 1 = B-half
    auto stageA = [&](int u, int half) {
        const int cbh2 = u / 9;
        const int tap = u - cbh2 * 9;
        const int koff = cbh2 * 128 + half * 64;
        char* Aq = smem + (u & 1) * 32768 + half * 16384;
        const unsigned char* asrc = wt + (size_t)tap * (C_ * C_) + koff;
        GLOAD_LDS16(asrc + a_off[0], Aq + t * 16);
        GLOAD_LDS16(asrc + a_off[1], Aq + (t + 512) * 16);
    };
    auto stageB = [&](int u, int half) {
        const int cbh2 = u / 9;
        const int tap = u - cbh2 * 9;
        const int kh = tap / 3, kw = tap - kh * 3;
        const int koff = cbh2 * 128 + half * 64;
        char* Bq = smem + 65536 + (u & 1) * 28672 + half * 14336;
        const unsigned char* bsrc = xt + (kh * HP + kw) * C_ + koff;
        GLOAD_LDS16(bsrc + x_off[0], Bq + t * 16);
        if (lw)
            GLOAD_LDS16(bsrc + x_off[1], Bq + (t + 512) * 16);
    };

    // prologue: stage(0) fully
    stageA(0, 0); stageA(0, 1); stageB(0, 0); stageB(0, 1);

    for (int u = 0; u < NSTEP; ++u) {
        WAITV0();                          // stage(u) landed (per-wave)
        __builtin_amdgcn_s_barrier();      // global: buf(u) ready; reads(u-1) done
        const int q = u & 1;
        const bool st = (u + 1 < NSTEP);

        #pragma unroll
        for (int half = 0; half < 2; ++half) {
            const char* Aq = smem + q * 32768 + half * 16384;
            const char* Bq = smem + 65536 + q * 28672 + half * 14336;
            int32x4 af[4], bf[7];
            #pragma unroll
            for (int m = 0; m < 4; ++m)
                af[m] = *reinterpret_cast<const int32x4*>(Aq + aoff[m]);
            #pragma unroll
            for (int nn = 0; nn < 7; ++nn)
                bf[nn] = *reinterpret_cast<const int32x4*>(Bq + boff[nn]);
            // prefetch: half0 issues A(u+1) both halves; half1 issues B(u+1)
            if (st) {
                if (half == 0) { stageA(u + 1, 0); stageA(u + 1, 1); }
                else           { stageB(u + 1, 0); stageB(u + 1, 1); }
            }
            __builtin_amdgcn_s_setprio(1);
            #pragma unroll
            for (int m = 0; m < 4; ++m)
                #pragma unroll
                for (int nn = 0; nn < 7; ++nn)
                    acc[m][nn] = __builtin_amdgcn_mfma_i32_16x16x64_i8(
                        af[m], bf[nn], acc[m][nn], 0, 0, 0);
            __builtin_amdgcn_s_setprio(0);
        }
    }

    // epilogue: D col = lane&15 (p), row = (lane>>4)*4 + j (co); scale by 1/26
    #pragma unroll
    for (int m = 0; m < 4; ++m) {
        #pragma unroll
        for (int j = 0; j < 4; ++j) {
            const int co = wm * 64 + m * 16 + (lane >> 4) * 4 + j;
            float* op = out + (size_t)(n * C_ + co) * SPATIAL + sp0 + wn * 112 + (lane & 15);
            #pragma unroll
            for (int nn = 0; nn < 7; ++nn)
                op[nn * 16] = (float)acc[m][nn][j] * QINV;
        }
    }
}

// ---------------- fallback (round-1 f32 direct conv) ----------------

__global__ __launch_bounds__(128) void bconv_f32_kernel(
    const float* __restrict__ x,
    const float* __restrict__ w,
    float* __restrict__ out)
{
    const int tx = threadIdx.x;
    const int ty = threadIdx.y;
    const int nc = blockIdx.x;
    const int co = nc & 255;
    const int h  = blockIdx.y * 8 + ty;
    const int w0 = tx * 4;
    if (tx >= 14) return;

    const float* xn = x + (size_t)(nc >> 8) * (C_ * H_ * W_);
    const float* wc = w + (size_t)co * (C_ * 9);
    float acc0 = 0.f, acc1 = 0.f, acc2 = 0.f, acc3 = 0.f;
    const bool rv0 = (h > 0), rv2 = (h < H_ - 1);
    const bool cvL = (tx != 0), cvR = (tx != 13);

    for (int ci = 0; ci < C_; ++ci) {
        const float* xc = xn + ci * (H_ * W_);
        const float* wk = wc + ci * 9;
        float v[3][6];
        #pragma unroll
        for (int r = 0; r < 3; ++r) {
            const bool rv = (r == 0) ? rv0 : (r == 2) ? rv2 : true;
            if (rv) {
                const float* rp = xc + (h + r - 1) * W_;
                const float4 m = *reinterpret_cast<const float4*>(rp + w0);
                v[r][1] = m.x; v[r][2] = m.y; v[r][3] = m.z; v[r][4] = m.w;
                v[r][0] = cvL ? rp[w0 - 1] : -1.0f;
                v[r][5] = cvR ? rp[w0 + 4] : -1.0f;
            } else {
                #pragma unroll
                for (int j = 0; j < 6; ++j) v[r][j] = -1.0f;
            }
        }
        #pragma unroll
        for (int r = 0; r < 3; ++r)
            #pragma unroll
            for (int c = 0; c < 3; ++c) {
                const float s = (wk[r * 3 + c] >= 0.f) ? 1.0f : -1.0f;
                acc0 = fmaf(s, v[r][c + 0], acc0);
                acc1 = fmaf(s, v[r][c + 1], acc1);
                acc2 = fmaf(s, v[r][c + 2], acc2);
                acc3 = fmaf(s, v[r][c + 3], acc3);
            }
    }
    float* op = out + ((size_t)nc * H_ + h) * W_ + w0;
    *reinterpret_cast<float4*>(op) = make_float4(acc0, acc1, acc2, acc3);
}

// ---------------- launch ----------------

extern "C" void kernel_launch(void* const* d_in, const int* in_sizes, int n_in,
                              void* d_out, int out_size, void* d_ws, size_t ws_size,
                              hipStream_t stream) {
    const float* x = (const float*)d_in[0];
    const float* w = (const float*)d_in[1];
    float* out = (float*)d_out;

    const size_t XT_OFF = 2u * 1024u * 1024u;                 // wt region (590KB)
    const size_t XT_BYTES = (size_t)N_ * HP * HP * C_;        // 27,557,888 (i8)
    const size_t NEEDED = XT_OFF + XT_BYTES;
    const int LDS_BYTES = 122880;   // A 2x32KB + B 2x28KB

    if (ws_size >= NEEDED) {
        char* wt = (char*)d_ws;
        unsigned char* xt = (unsigned char*)((char*)d_ws + XT_OFF);
        hipFuncSetAttribute((const void*)&bgemm,
                            hipFuncAttributeMaxDynamicSharedMemorySize, LDS_BYTES);
        xform_w<<<256, 256, 0, stream>>>(w, wt);
        xform_x<<<N_ * H_, 256, 0, stream>>>(x, xt);
        bgemm<<<NBLK, 512, LDS_BYTES, stream>>>(xt, (const unsigned char*)wt, out);
    } else {
        dim3 block(16, 8);
        dim3 grid(N_ * 256, H_ / 8);
        bconv_f32_kernel<<<grid, block, 0, stream>>>(x, w, out);
    }
}